// Round 17
// baseline (70.604 us; speedup 1.0000x reference)
//
#include <hip/hip_runtime.h>
#include <hip/hip_bf16.h>
#include <math.h>

typedef float v2f __attribute__((ext_vector_type(2)));
typedef __attribute__((ext_vector_type(8))) short bf16x8;
typedef __attribute__((ext_vector_type(4))) float f32x4;
typedef __attribute__((ext_vector_type(4))) int i32x4;

#define N_POINTS 32768
#define NUM_EMBED 8192
#define CH 64                                // chunks (fits 64-bit survivor mask)
#define CPC (NUM_EMBED / CH)                 // 128 candidates per chunk
#define RB 1024                              // resolve block threads (16 waves, 16 points)
#define RPB (RB / 64)                        // 16 points per resolve block
#define FWAVES 4                             // filter waves per block
#define CSTRIDE 4096                         // 64*64, channel stride in z [B,C,H,W]

// round-to-nearest bf16 (rel err <= 2^-8), bit pattern
__device__ __forceinline__ unsigned int bfr(float f) {
    __hip_bfloat16 h = __float2bfloat16(f);
    return (unsigned int)*reinterpret_cast<unsigned short*>(&h);
}
__device__ __forceinline__ uint2 pack4(float a, float b, float c, float d) {
    return make_uint2(bfr(a) | (bfr(b) << 16), bfr(c) | (bfr(d) << 16));
}

// order-preserving bijection float -> uint32 (total order == float <)
__device__ __forceinline__ unsigned int fkey(float f) {
    unsigned int b = __float_as_uint(f);
    return b ^ (0x80000000u | (unsigned int)((int)b >> 31));
}

// ---------------- kernel A: pack z and E to bf16 [idx][k] (8B each)
__global__ void vq_pack_kernel(const float* __restrict__ z, const float4* __restrict__ E,
                               uint2* __restrict__ zbf, uint2* __restrict__ ebf) {
    int i = blockIdx.x * 256 + threadIdx.x;
    if (i < N_POINTS) {
        int b = i >> 12, hw = i & 4095;
        const float* zp = z + b * 16384 + hw;
        zbf[i] = pack4(zp[0], zp[CSTRIDE], zp[2 * CSTRIDE], zp[3 * CSTRIDE]);
    }
    if (i < NUM_EMBED) {
        float4 e = E[i];
        ebf[i] = pack4(e.x, e.y, e.z, e.w);
    }
}

// ---------------- kernel B (filter): bf16 MFMA dot-max per (point, chunk)
// One wave owns 16 points (B-frag, constant) and loops 512 candidate tiles (A-frag).
// C layout (m89-verified): col=lane&15 (point), row=(lane>>4)*4+reg (candidate).
// Per chunk (8 tiles): fold 4 C-regs per tile into per-lane run-max (32 candidates),
// then shfl_xor(16,32) folds the 4 row-groups -> per-point chunk max.
__global__ __launch_bounds__(256) void vq_mfma_filter(
        const uint2* __restrict__ zbf, const uint2* __restrict__ ebf,
        float* __restrict__ cmax) {
    const int lane = threadIdx.x & 63;
    const int wid = threadIdx.x >> 6;
    const int wv = blockIdx.x * FWAVES + wid;    // 0..2047
    const int n0 = wv * 16;

    const bool lo = lane < 16;
    // B fragment: points. lane l (l<16): B[k=0..7][col=l] = z_bf[n0+l][k] (k>=4 zero).
    uint2 zl = zbf[n0 + (lane & 15)];
    i32x4 bi = { lo ? (int)zl.x : 0, lo ? (int)zl.y : 0, 0, 0 };
    bf16x8 bfrag = *(bf16x8*)&bi;
    const f32x4 zero4 = {0.f, 0.f, 0.f, 0.f};

    for (int c = 0; c < CH; ++c) {
        float rm = -__builtin_inff();
        #pragma unroll
        for (int t = 0; t < 8; ++t) {
            int j0 = (c * 8 + t) * 16;
            // A fragment: candidates. lane l (l<16): A[row=l][k=0..7] = e_bf[j0+l][k].
            uint2 el = ebf[j0 + (lane & 15)];
            i32x4 ai = { lo ? (int)el.x : 0, lo ? (int)el.y : 0, 0, 0 };
            bf16x8 afrag = *(bf16x8*)&ai;
            f32x4 d = __builtin_amdgcn_mfma_f32_16x16x32_bf16(afrag, bfrag, zero4, 0, 0, 0);
            rm = fmaxf(rm, fmaxf(fmaxf(d[0], d[1]), fmaxf(d[2], d[3])));
        }
        rm = fmaxf(rm, __shfl_xor(rm, 16));
        rm = fmaxf(rm, __shfl_xor(rm, 32));
        if (lo) cmax[(size_t)c * N_POINTS + n0 + lane] = rm;   // 64B line per wave
    }
}

// ---------------- kernel C (resolve): 16 waves / 16 points per block (r16-proven).
// Phase 1: full-line tile load of cmax into padded LDS. Phase 2 per wave: shfl gmax;
// threshold = gmax - (2u + 1e-7  [r9-proven chain window]  + 2E_bf16 + margin);
// ballot survivor mask; coalesced EXACT-chain rescan; 64-bit key min = first-index argmin.
__global__ __launch_bounds__(RB) void vq_resolve_kernel(
        const float* __restrict__ z, const float4* __restrict__ E,
        const float* __restrict__ cmax,
        float* __restrict__ out, double* __restrict__ partial) {
    __shared__ float sCm[CH][RPB + 1];
    __shared__ double sdata[RPB];
    const int lane = threadIdx.x & 63;
    const int wid = threadIdx.x >> 6;
    const int n0 = blockIdx.x * RPB;
    const int n = n0 + wid;

    {
        int t = threadIdx.x;
        sCm[t >> 4][t & 15] = cmax[(size_t)(t >> 4) * N_POINTS + n0 + (t & 15)];
    }

    const int b = n >> 12;
    const int hw = n & 4095;
    const float* zp = z + b * 16384 + hw;
    float z0 = zp[0];
    float z1 = zp[CSTRIDE];
    float z2 = zp[2 * CSTRIDE];
    float z3 = zp[3 * CSTRIDE];
    float zz = __fmul_rn(z0, z0);
    zz = __fadd_rn(zz, __fmul_rn(z1, z1));
    zz = __fadd_rn(zz, __fmul_rn(z2, z2));
    zz = __fadd_rn(zz, __fmul_rn(z3, z3));

    __syncthreads();

    float cm = sCm[lane][wid];
    float gmax = cm;
    #pragma unroll
    for (int off = 32; off; off >>= 1)
        gmax = fmaxf(gmax, __shfl_xor(gmax, off));

    // chain-rounding window (r9-proven): 2u + 1e-7, u = (zz+.01)*2^-22
    // bf16-filter drift: 2E, E <= L1(z)*1e-6  (|dot_bf - dot_chain| bound; RN bf16)
    float u = __fmul_rn(__fadd_rn(zz, 0.01f), 2.38418579e-07f);
    float L1 = __fadd_rn(__fadd_rn(fabsf(z0), fabsf(z1)), __fadd_rn(fabsf(z2), fabsf(z3)));
    float slack = __fadd_rn(__fadd_rn(u, u), __fmaf_rn(L1, 2.0e-6f, 2.0e-7f));
    float thr = __fsub_rn(gmax, slack);
    unsigned long long mask = __ballot(cm >= thr);   // wave-uniform, >=1 bit set

    // exact rescan of surviving chunks (coalesced: lane -> j0+lane, j0+64+lane)
    unsigned long long bkey = ~0ull;
    while (mask) {
        int c = __builtin_ctzll(mask);
        mask &= mask - 1ull;
        int j0 = c * CPC + lane;
        #pragma unroll
        for (int h = 0; h < 2; ++h) {
            int j = j0 + h * 64;
            float4 e = E[j];
            float ee = __fmul_rn(e.x, e.x);
            ee = __fadd_rn(ee, __fmul_rn(e.y, e.y));
            ee = __fadd_rn(ee, __fmul_rn(e.z, e.z));
            ee = __fadd_rn(ee, __fmul_rn(e.w, e.w));
            float dot = __fmul_rn(z0, e.x);
            dot = __fmaf_rn(z1, e.y, dot);
            dot = __fmaf_rn(z2, e.z, dot);
            dot = __fmaf_rn(z3, e.w, dot);
            float d = __fmaf_rn(-2.0f, dot, __fadd_rn(zz, ee));
            unsigned long long key =
                ((unsigned long long)fkey(d) << 32) | (unsigned int)j;
            bkey = key < bkey ? key : bkey;
        }
    }
    #pragma unroll
    for (int off = 32; off; off >>= 1) {
        unsigned long long o = __shfl_xor(bkey, off);
        bkey = o < bkey ? o : bkey;
    }
    int besti = (int)(unsigned int)(bkey & 0xFFFFFFFFull);

    if (lane == 0) {
        float4 e = E[besti];
        float* op = out + b * 16384 + hw;
        float t0 = __fsub_rn(e.x, z0);
        float t1 = __fsub_rn(e.y, z1);
        float t2 = __fsub_rn(e.z, z2);
        float t3 = __fsub_rn(e.w, z3);
        op[0]           = __fadd_rn(z0, t0);     // straight-through: z + (z_q - z)
        op[CSTRIDE]     = __fadd_rn(z1, t1);
        op[2 * CSTRIDE] = __fadd_rn(z2, t2);
        op[3 * CSTRIDE] = __fadd_rn(z3, t3);
        out[131073 + n] = (float)besti;          // indices as float32 (exact)
        double ds = (double)__fmul_rn(t0, t0) + (double)__fmul_rn(t1, t1)
                  + (double)__fmul_rn(t2, t2) + (double)__fmul_rn(t3, t3);
        sdata[wid] = ds;
    }
    __syncthreads();
    if (threadIdx.x == 0) {
        double s = 0.0;
        #pragma unroll
        for (int w = 0; w < RPB; ++w) s += sdata[w];
        partial[blockIdx.x] = s;
    }
}

// ---------------- kernel D: deterministic loss reduce (2048 partials)
__global__ void vq_loss_kernel(const double* __restrict__ partial, float* __restrict__ out) {
    __shared__ double sdata[256];
    int t = threadIdx.x;
    double s = 0.0;
    for (int i = t; i < 2048; i += 256) s += partial[i];
    sdata[t] = s;
    __syncthreads();
    #pragma unroll
    for (int st = 128; st > 0; st >>= 1) {
        if (t < st) sdata[t] += sdata[t + st];
        __syncthreads();
    }
    if (t == 0) {
        float m = (float)(sdata[0] / 131072.0);
        // loss = mean + BETA*mean (both means are numerically identical)
        out[131072] = __fadd_rn(m, __fmul_rn(0.25f, m));
    }
}

extern "C" void kernel_launch(void* const* d_in, const int* in_sizes, int n_in,
                              void* d_out, int out_size, void* d_ws, size_t ws_size,
                              hipStream_t stream) {
    const float* z = (const float*)d_in[0];
    const float4* E = (const float4*)d_in[1];
    float* out = (float*)d_out;

    char* ws = (char*)d_ws;
    uint2* zbf = (uint2*)ws;                                  // 256 KB
    uint2* ebf = (uint2*)(ws + 262144);                       // 64 KB
    float* cmaxb = (float*)(ws + 262144 + 65536);             // 8 MB, [c][n]
    double* partial = (double*)(ws + 262144 + 65536 + (size_t)CH * N_POINTS * 4);  // 16 KB

    vq_pack_kernel<<<N_POINTS / 256, 256, 0, stream>>>(z, E, zbf, ebf);
    vq_mfma_filter<<<(N_POINTS / 16) / FWAVES, 256, 0, stream>>>(zbf, ebf, cmaxb);
    vq_resolve_kernel<<<N_POINTS / RPB, RB, 0, stream>>>(z, E, cmaxb, out, partial);
    vq_loss_kernel<<<1, 256, 0, stream>>>(partial, out);
}

// Round 18
// 59.788 us; speedup vs baseline: 1.1809x; 1.1809x over previous
//
#include <hip/hip_runtime.h>
#include <hip/hip_bf16.h>
#include <math.h>

typedef __attribute__((ext_vector_type(8))) short bf16x8;
typedef __attribute__((ext_vector_type(4))) float f32x4;
typedef __attribute__((ext_vector_type(4))) int i32x4;

#define N_POINTS 32768
#define NUM_EMBED 8192
#define CH 64                                // chunks (fits 64-bit survivor mask)
#define CPC (NUM_EMBED / CH)                 // 128 candidates per chunk
#define CSTRIDE 4096                         // 64*64, channel stride in z [B,C,H,W]

// round-to-nearest bf16 (rel err <= 2^-8), bit pattern
__device__ __forceinline__ unsigned int bfr(float f) {
    __hip_bfloat16 h = __float2bfloat16(f);
    return (unsigned int)*reinterpret_cast<unsigned short*>(&h);
}
__device__ __forceinline__ uint2 pack4(float a, float b, float c, float d) {
    return make_uint2(bfr(a) | (bfr(b) << 16), bfr(c) | (bfr(d) << 16));
}

// order-preserving bijection float -> uint32 (total order == float <)
__device__ __forceinline__ unsigned int fkey(float f) {
    unsigned int b = __float_as_uint(f);
    return b ^ (0x80000000u | (unsigned int)((int)b >> 31));
}

// ---------------- kernel A: pack E to bf16 [j][k] (8B each)
__global__ void vq_pack_kernel(const float4* __restrict__ E, uint2* __restrict__ ebf) {
    int i = blockIdx.x * 256 + threadIdx.x;
    if (i < NUM_EMBED) {
        float4 e = E[i];
        ebf[i] = pack4(e.x, e.y, e.z, e.w);
    }
}

// ---------------- kernel B (fused filter+resolve): block = 4 waves = 16 points.
// Stage 1 (r17-proven MFMA filter, chunk-split): wave wid computes chunks
// [wid*16, wid*16+16) x 16 points. C layout (m89-verified): col=lane&15 (point),
// row=(lane>>4)*4+reg (candidate). Chunk-max -> padded LDS sCm[64][17].
// Stage 2 (r16/r17-proven resolve): wave wid resolves points wid*4..wid*4+3:
// shfl gmax; threshold = gmax - (2u+1e-7 [chain window] + 2*L1*1e-6+2e-7 [bf16 drift]);
// ballot survivors; coalesced EXACT-chain rescan; 64-bit key min = first-index argmin.
__global__ __launch_bounds__(256) void vq_fused_kernel(
        const float* __restrict__ z, const uint2* __restrict__ ebf,
        const float4* __restrict__ E,
        float* __restrict__ out, double* __restrict__ partial) {
    __shared__ float sCm[CH][17];                // 4.3 KB, odd stride: conflict-free
    __shared__ double sLoss[16];
    const int lane = threadIdx.x & 63;
    const int wid = threadIdx.x >> 6;
    const int n0 = blockIdx.x * 16;

    // ---- B fragment: this block's 16 points, bf16-packed in-register
    const bool lo = lane < 16;
    {
        int n = n0 + (lane & 15);
        int b = n >> 12, hw = n & 4095;
        const float* zp = z + b * 16384 + hw;
        uint2 zl = pack4(zp[0], zp[CSTRIDE], zp[2 * CSTRIDE], zp[3 * CSTRIDE]);
        i32x4 bi = { lo ? (int)zl.x : 0, lo ? (int)zl.y : 0, 0, 0 };
        bf16x8 bfrag = *(bf16x8*)&bi;
        const f32x4 zero4 = {0.f, 0.f, 0.f, 0.f};

        // ---- stage 1: 16 chunks per wave
        for (int ci = 0; ci < 16; ++ci) {
            int c = wid * 16 + ci;
            float rm = -__builtin_inff();
            #pragma unroll
            for (int t = 0; t < 8; ++t) {
                int j0 = (c * 8 + t) * 16;
                uint2 el = ebf[j0 + (lane & 15)];
                i32x4 ai = { lo ? (int)el.x : 0, lo ? (int)el.y : 0, 0, 0 };
                bf16x8 afrag = *(bf16x8*)&ai;
                f32x4 d = __builtin_amdgcn_mfma_f32_16x16x32_bf16(afrag, bfrag, zero4, 0, 0, 0);
                rm = fmaxf(rm, fmaxf(fmaxf(d[0], d[1]), fmaxf(d[2], d[3])));
            }
            rm = fmaxf(rm, __shfl_xor(rm, 16));
            rm = fmaxf(rm, __shfl_xor(rm, 32));
            if (lo) sCm[c][lane] = rm;
        }
    }
    __syncthreads();

    // ---- stage 2: wave wid resolves 4 points
    for (int q = 0; q < 4; ++q) {
        int pl = wid * 4 + q;
        int n = n0 + pl;
        int b = n >> 12, hw = n & 4095;
        const float* zp = z + b * 16384 + hw;      // wave-uniform broadcast loads
        float z0 = zp[0];
        float z1 = zp[CSTRIDE];
        float z2 = zp[2 * CSTRIDE];
        float z3 = zp[3 * CSTRIDE];
        float zz = __fmul_rn(z0, z0);
        zz = __fadd_rn(zz, __fmul_rn(z1, z1));
        zz = __fadd_rn(zz, __fmul_rn(z2, z2));
        zz = __fadd_rn(zz, __fmul_rn(z3, z3));

        float cm = sCm[lane][pl];                  // lane = chunk; stride 17: conflict-free
        float gmax = cm;
        #pragma unroll
        for (int off = 32; off; off >>= 1)
            gmax = fmaxf(gmax, __shfl_xor(gmax, off));

        float u = __fmul_rn(__fadd_rn(zz, 0.01f), 2.38418579e-07f);
        float L1 = __fadd_rn(__fadd_rn(fabsf(z0), fabsf(z1)),
                             __fadd_rn(fabsf(z2), fabsf(z3)));
        float slack = __fadd_rn(__fadd_rn(u, u), __fmaf_rn(L1, 2.0e-6f, 2.0e-7f));
        float thr = __fsub_rn(gmax, slack);
        unsigned long long mask = __ballot(cm >= thr);   // wave-uniform, >=1 bit set

        unsigned long long bkey = ~0ull;
        while (mask) {
            int c = __builtin_ctzll(mask);
            mask &= mask - 1ull;
            int j0 = c * CPC + lane;
            #pragma unroll
            for (int h = 0; h < 2; ++h) {
                int j = j0 + h * 64;
                float4 e = E[j];
                float ee = __fmul_rn(e.x, e.x);
                ee = __fadd_rn(ee, __fmul_rn(e.y, e.y));
                ee = __fadd_rn(ee, __fmul_rn(e.z, e.z));
                ee = __fadd_rn(ee, __fmul_rn(e.w, e.w));
                float dot = __fmul_rn(z0, e.x);
                dot = __fmaf_rn(z1, e.y, dot);
                dot = __fmaf_rn(z2, e.z, dot);
                dot = __fmaf_rn(z3, e.w, dot);
                float d = __fmaf_rn(-2.0f, dot, __fadd_rn(zz, ee));
                unsigned long long key =
                    ((unsigned long long)fkey(d) << 32) | (unsigned int)j;
                bkey = key < bkey ? key : bkey;
            }
        }
        #pragma unroll
        for (int off = 32; off; off >>= 1) {
            unsigned long long o = __shfl_xor(bkey, off);
            bkey = o < bkey ? o : bkey;
        }
        int besti = (int)(unsigned int)(bkey & 0xFFFFFFFFull);

        if (lane == 0) {
            float4 e = E[besti];
            float* op = out + b * 16384 + hw;
            float t0 = __fsub_rn(e.x, z0);
            float t1 = __fsub_rn(e.y, z1);
            float t2 = __fsub_rn(e.z, z2);
            float t3 = __fsub_rn(e.w, z3);
            op[0]           = __fadd_rn(z0, t0); // straight-through: z + (z_q - z)
            op[CSTRIDE]     = __fadd_rn(z1, t1);
            op[2 * CSTRIDE] = __fadd_rn(z2, t2);
            op[3 * CSTRIDE] = __fadd_rn(z3, t3);
            out[131073 + n] = (float)besti;      // indices as float32 (exact)
            sLoss[pl] = (double)__fmul_rn(t0, t0) + (double)__fmul_rn(t1, t1)
                      + (double)__fmul_rn(t2, t2) + (double)__fmul_rn(t3, t3);
        }
    }
    __syncthreads();
    if (threadIdx.x == 0) {
        double s = 0.0;
        #pragma unroll
        for (int w = 0; w < 16; ++w) s += sLoss[w];
        partial[blockIdx.x] = s;
    }
}

// ---------------- kernel C: deterministic loss reduce (2048 partials)
__global__ void vq_loss_kernel(const double* __restrict__ partial, float* __restrict__ out) {
    __shared__ double sdata[256];
    int t = threadIdx.x;
    double s = 0.0;
    for (int i = t; i < 2048; i += 256) s += partial[i];
    sdata[t] = s;
    __syncthreads();
    #pragma unroll
    for (int st = 128; st > 0; st >>= 1) {
        if (t < st) sdata[t] += sdata[t + st];
        __syncthreads();
    }
    if (t == 0) {
        float m = (float)(sdata[0] / 131072.0);
        // loss = mean + BETA*mean (both means are numerically identical)
        out[131072] = __fadd_rn(m, __fmul_rn(0.25f, m));
    }
}

extern "C" void kernel_launch(void* const* d_in, const int* in_sizes, int n_in,
                              void* d_out, int out_size, void* d_ws, size_t ws_size,
                              hipStream_t stream) {
    const float* z = (const float*)d_in[0];
    const float4* E = (const float4*)d_in[1];
    float* out = (float*)d_out;

    char* ws = (char*)d_ws;
    uint2* ebf = (uint2*)ws;                                  // 64 KB
    double* partial = (double*)(ws + 65536);                  // 16 KB

    vq_pack_kernel<<<NUM_EMBED / 256, 256, 0, stream>>>(E, ebf);
    vq_fused_kernel<<<N_POINTS / 16, 256, 0, stream>>>(z, ebf, E, out, partial);
    vq_loss_kernel<<<1, 256, 0, stream>>>(partial, out);
}